// Round 6
// baseline (839.506 us; speedup 1.0000x reference)
//
#include <hip/hip_runtime.h>
#include <hip/hip_bf16.h>

#define GLOBAL_AS __attribute__((address_space(1)))
#define LDS_AS    __attribute__((address_space(3)))

typedef __bf16 bf16_t;
typedef __bf16 bf16x8 __attribute__((ext_vector_type(8)));
typedef __bf16 bf16x4 __attribute__((ext_vector_type(4)));
typedef float  f32x4  __attribute__((ext_vector_type(4)));
typedef _Float16 fp16_t;
typedef _Float16 fp16x8 __attribute__((ext_vector_type(8)));

static constexpr int Bb = 256;    // batch
static constexpr int Ss = 14;     // seq
static constexpr int Hh = 1024;   // hidden
static constexpr int Cc = 2513;   // classes
static constexpr int NXc = 3584;  // B*S
static constexpr int Kk = 1024;   // K (== F == H)

__device__ __forceinline__ float sigm(float x)   { return 1.0f / (1.0f + __expf(-x)); }
__device__ __forceinline__ float tanh_f(float x) { return 2.0f / (1.0f + __expf(-2.0f * x)) - 1.0f; }

// ---------------------------------------------------------------------------
// 128x256-tile (col-pair) bf16 GEMM: one A tile + two B tiles per K-step.
// K=1024, BK=64, single-buffered r3 sync skeleton (stage -> sync -> compute
// -> sync). LDS 48KB. 64 MFMA/wave per barrier window (2x r3's intensity),
// A-staging traffic -25%, and all grids <= 512 blocks -> one uniform round
// at ~2 blocks/CU (kills fractional-round tails, the r3 residual).
// EPI 2: classifier — A rows remapped row -> (row%14)*256 + row/14; add
//        col-bias; fp32 store. CB counts COL-PAIRS (256 cols each).
// ---------------------------------------------------------------------------
template<int EPI>
__global__ __launch_bounds__(256, 2)
void gemm_bt(const bf16_t* __restrict__ A, const bf16_t* __restrict__ Bm,
             int N, int rpg, int cpg, int CG, int CB,
             const float* __restrict__ e_bias,
             bf16_t* __restrict__ xg_bf,
             float* __restrict__ fout)
{
    const int lin = blockIdx.x;
    const int xcd = lin & 7;
    const int per = lin >> 3;
    const int rg = xcd / CG, cg = xcd % CG;
    const int rb = rg * rpg + per % rpg;
    const int cb = cg * cpg + per / rpg;
    if (cb >= CB) return;

    __shared__ char smem[49152];                // A 16K | B0 16K | B1 16K
    LDS_AS char* sA  = (LDS_AS char*)smem;
    LDS_AS char* sB0 = sA + 16384;
    LDS_AS char* sB1 = sA + 32768;

    const int tid  = threadIdx.x;
    const int lane = tid & 63;
    const int wave = tid >> 6;
    const int row0 = rb * 128;
    const int col0 = cb * 256;
    const int mwb  = (wave >> 1) * 64;
    const int nwb  = (wave & 1) * 64;
    const int quad = lane >> 4;
    const int l15  = lane & 15;

    f32x4 accL[4][4] = {};
    f32x4 accR[4][4] = {};

    for (int kb = 0; kb < Kk; kb += 64) {
#pragma unroll
        for (int it = 0; it < 4; ++it) {
            int c  = it * 256 + tid;
            int m  = c >> 3;
            int kq = (c & 7) ^ (m & 7);
            size_t arow;
            if (EPI == 2) {                      // A-row remap: b*14+s -> s*256+b
                int row = row0 + m;
                int bb = row / 14;
                int ss = row - bb * 14;
                arow = (size_t)(ss * 256 + bb);
            } else {
                arow = (size_t)(row0 + m);
            }
            const bf16_t* ga = A + arow * Kk + kb + kq * 8;
            int nr0 = col0 + m;
            int nr1 = col0 + 128 + m;
            if (EPI == 2) { if (nr0 >= N) nr0 = 0; if (nr1 >= N) nr1 = 0; }
            const bf16_t* gb0 = Bm + (size_t)nr0 * Kk + kb + kq * 8;
            const bf16_t* gb1 = Bm + (size_t)nr1 * Kk + kb + kq * 8;
            const size_t lofs = (size_t)(it * 256 + (tid & 192)) * 16;
            __builtin_amdgcn_global_load_lds((const GLOBAL_AS void*)ga,  (LDS_AS void*)(sA  + lofs), 16, 0, 0);
            __builtin_amdgcn_global_load_lds((const GLOBAL_AS void*)gb0, (LDS_AS void*)(sB0 + lofs), 16, 0, 0);
            __builtin_amdgcn_global_load_lds((const GLOBAL_AS void*)gb1, (LDS_AS void*)(sB1 + lofs), 16, 0, 0);
        }
        __syncthreads();

#pragma unroll
        for (int kt = 0; kt < 2; ++kt) {
            bf16x8 af[4], bfL[4], bfR[4];
            const int kq = kt * 4 + quad;
#pragma unroll
            for (int i = 0; i < 4; ++i) {
                int ml = mwb + i * 16 + l15;
                af[i]  = *(const LDS_AS bf16x8*)(sA  + (size_t)(ml * 8 + (kq ^ (ml & 7))) * 16);
                int nl = nwb + i * 16 + l15;
                bfL[i] = *(const LDS_AS bf16x8*)(sB0 + (size_t)(nl * 8 + (kq ^ (nl & 7))) * 16);
                bfR[i] = *(const LDS_AS bf16x8*)(sB1 + (size_t)(nl * 8 + (kq ^ (nl & 7))) * 16);
            }
#pragma unroll
            for (int i = 0; i < 4; ++i)
#pragma unroll
                for (int j = 0; j < 4; ++j) {
                    accL[i][j] = __builtin_amdgcn_mfma_f32_16x16x32_bf16(af[i], bfL[j], accL[i][j], 0, 0, 0);
                    accR[i][j] = __builtin_amdgcn_mfma_f32_16x16x32_bf16(af[i], bfR[j], accR[i][j], 0, 0, 0);
                }
        }
        __syncthreads();
    }

#pragma unroll
    for (int half = 0; half < 2; ++half) {
#pragma unroll
        for (int im = 0; im < 4; ++im) {
#pragma unroll
            for (int jn = 0; jn < 4; ++jn) {
                const int rr  = row0 + mwb + im * 16 + quad * 4;
                const int col = col0 + half * 128 + nwb + jn * 16 + l15;
                f32x4 v = half ? accR[im][jn] : accL[im][jn];
                if (EPI == 0) {
                    const int n = rr >> 2;
                    f32x4 bi = *(const f32x4*)(e_bias + n * 4);
                    bf16x4 o;
                    o[0] = (bf16_t)(v[0] + bi[0]); o[1] = (bf16_t)(v[1] + bi[1]);
                    o[2] = (bf16_t)(v[2] + bi[2]); o[3] = (bf16_t)(v[3] + bi[3]);
                    *(bf16x4*)(xg_bf + ((size_t)n * NXc + col) * 4) = o;
                } else {
                    if (col < N) {
                        float bi = e_bias[col];
#pragma unroll
                        for (int g = 0; g < 4; ++g)
                            fout[(size_t)(rr + g) * N + col] = v[g] + bi;
                    }
                }
            }
        }
    }
}

// ---------------------------------------------------------------------------
// Merged recurrent step (skewed schedule, global step k), col-pair tiles:
//   recurrent region (blocks < nRec, XCD 2D map):
//     unroll col-pairs [0, UCP): A=Au, advance t<=k-2 lockstep
//     roll col-pair   [UCP, CP): A=Ar, compute hs[k-1] (exactly 1 pair)
//   xproj filler blocks (blocks >= nRec): 128x256 tiles of the input-
//     projection GEMM (chunk c<14 = roll cols c*256; c>=14 = unroll cols
//     (c-14)*256; 32 blocks/chunk), scheduled into steps 1-2.
// K-loop: r3-verified skeleton (stage -> sync -> compute -> sync), 48KB LDS.
// Epilogue: gates (+xg) bounced through swizzled LDS (per 128-col half) so
// c-read / h,c-writes are coalesced 16B vector ops.
// h ping-pong bf16, c ping-pong fp16.
// ---------------------------------------------------------------------------
struct StepArgs {
    const bf16_t* Au;     // unroll weight [4096,1024] perm-rows
    const bf16_t* Ar;     // roll weight
    const bf16_t* Bh;     // h read base (P[(k-1)&1]; h0 for k==1)
    const bf16_t* xg_u;   // XGu [n][col][4]
    const bf16_t* xg_r;   // XGr
    const fp16_t* c_r;    // c read base
    fp16_t*       c_w;    // c write base
    bf16_t*       h_w;    // h write base
    const bf16_t* Wih;    // [8192,1024] perm-rows (roll | unroll)
    const bf16_t* Xb;     // x_b [s*256+b][1024]
    const float*  bias2;  // [8192] fused biases (roll | unroll)
    bf16_t*       XG2;    // XG output base (n absolute 0..2048)
    int UCP;              // unroll col-pairs (= a)
    int b_off;            // roll B col offset   = (k-2)*256
    int xg_off;           // roll xg col offset  = (k-1)*256
    int cr_off;           // roll c-read offset  = (k-2)*256
    int cw_off;           // roll c/h-write off  = (k-1)*256
    int CP, cppg;         // total col-pairs, col-pairs per XCD group
    int nRec;             // blocks below this: recurrent region
    int xp[15];           // xproj chunk ids for this step
};

__global__ __launch_bounds__(256, 2)
void lstm_step(StepArgs p)
{
    const int tid  = threadIdx.x;
    const int lane = tid & 63;
    const int wave = tid >> 6;
    const int mwb  = (wave >> 1) * 64;
    const int nwb  = (wave & 1) * 64;
    const int quad = lane >> 4;
    const int l15  = lane & 15;

    __shared__ char smem[49152];                // A 16K | B0 16K | B1 16K
    LDS_AS char* sA  = (LDS_AS char*)smem;
    LDS_AS char* sB0 = sA + 16384;
    LDS_AS char* sB1 = sA + 32768;

    const bf16_t* A;
    const bf16_t* Bbase;
    int row0, bcol0;
    bool isxp;
    bool roll = false;
    int  colp = 0;

    if ((int)blockIdx.x >= p.nRec) {
        isxp = true;
        const int idx = (int)blockIdx.x - p.nRec;
        const int c   = p.xp[idx >> 5];
        const int isu = (c >= 14) ? 1 : 0;
        const int j   = c - isu * 14;
        const int rb  = idx & 31;
        row0  = isu * 4096 + rb * 128;      // absolute row in [0,8192)
        bcol0 = j * 256;                    // absolute col in [0,3584)
        A     = p.Wih;
        Bbase = p.Xb;
    } else {
        isxp = false;
        const int lin = blockIdx.x;
        const int xcd = lin & 7;
        const int per = lin >> 3;
        const int rb = (xcd >> 2) * 16 + (per & 15);
        const int cp = (xcd & 3) * p.cppg + (per >> 4);
        if (cp >= p.CP) return;
        roll = (cp >= p.UCP);
        colp = roll ? (cp - p.UCP) : cp;
        A     = roll ? p.Ar : p.Au;
        Bbase = p.Bh;
        row0  = rb * 128;
        bcol0 = colp * 256 + (roll ? p.b_off : 0);
    }

    f32x4 accL[4][4] = {};
    f32x4 accR[4][4] = {};

    for (int kb = 0; kb < Kk; kb += 64) {
#pragma unroll
        for (int it = 0; it < 4; ++it) {
            int c  = it * 256 + tid;
            int m  = c >> 3;
            int kq = (c & 7) ^ (m & 7);
            const bf16_t* ga  = A     + (size_t)(row0  + m) * Kk + kb + kq * 8;
            const bf16_t* gb0 = Bbase + (size_t)(bcol0 + m) * Kk + kb + kq * 8;
            const bf16_t* gb1 = Bbase + (size_t)(bcol0 + 128 + m) * Kk + kb + kq * 8;
            const size_t lofs = (size_t)(it * 256 + (tid & 192)) * 16;
            __builtin_amdgcn_global_load_lds((const GLOBAL_AS void*)ga,  (LDS_AS void*)(sA  + lofs), 16, 0, 0);
            __builtin_amdgcn_global_load_lds((const GLOBAL_AS void*)gb0, (LDS_AS void*)(sB0 + lofs), 16, 0, 0);
            __builtin_amdgcn_global_load_lds((const GLOBAL_AS void*)gb1, (LDS_AS void*)(sB1 + lofs), 16, 0, 0);
        }
        __syncthreads();

#pragma unroll
        for (int kt = 0; kt < 2; ++kt) {
            bf16x8 af[4], bfL[4], bfR[4];
            const int kq = kt * 4 + quad;
#pragma unroll
            for (int i = 0; i < 4; ++i) {
                int ml = mwb + i * 16 + l15;
                af[i]  = *(const LDS_AS bf16x8*)(sA  + (size_t)(ml * 8 + (kq ^ (ml & 7))) * 16);
                int nl = nwb + i * 16 + l15;
                bfL[i] = *(const LDS_AS bf16x8*)(sB0 + (size_t)(nl * 8 + (kq ^ (nl & 7))) * 16);
                bfR[i] = *(const LDS_AS bf16x8*)(sB1 + (size_t)(nl * 8 + (kq ^ (nl & 7))) * 16);
            }
#pragma unroll
            for (int i = 0; i < 4; ++i)
#pragma unroll
                for (int j = 0; j < 4; ++j) {
                    accL[i][j] = __builtin_amdgcn_mfma_f32_16x16x32_bf16(af[i], bfL[j], accL[i][j], 0, 0, 0);
                    accR[i][j] = __builtin_amdgcn_mfma_f32_16x16x32_bf16(af[i], bfR[j], accR[i][j], 0, 0, 0);
                }
        }
        __syncthreads();
    }

    if (isxp) {
        // input-projection epilogue: add row-bias, store bf16x4 to XG[n][col][4]
#pragma unroll
        for (int half = 0; half < 2; ++half) {
#pragma unroll
            for (int im = 0; im < 4; ++im) {
#pragma unroll
                for (int jn = 0; jn < 4; ++jn) {
                    const int rr  = row0 + mwb + im * 16 + quad * 4;
                    const int col = bcol0 + half * 128 + nwb + jn * 16 + l15;
                    f32x4 v = half ? accR[im][jn] : accL[im][jn];
                    const int n = rr >> 2;
                    f32x4 bi = *(const f32x4*)(p.bias2 + n * 4);
                    bf16x4 o;
                    o[0] = (bf16_t)(v[0] + bi[0]); o[1] = (bf16_t)(v[1] + bi[1]);
                    o[2] = (bf16_t)(v[2] + bi[2]); o[3] = (bf16_t)(v[3] + bi[3]);
                    *(bf16x4*)(p.XG2 + ((size_t)n * NXc + col) * 4) = o;
                }
            }
        }
        return;
    }

    const bf16_t* xg = roll ? p.xg_r : p.xg_u;
    const int xo  = roll ? p.xg_off : 0;
    const int cro = roll ? p.cr_off : 0;
    const int cwo = roll ? p.cw_off : 0;
    const int nbase = row0 >> 2;                 // 32-aligned
    LDS_AS f32x4* sG = (LDS_AS f32x4*)smem;

    // per 128-col half: fold xg into acc, LDS bounce (64 cols x 32 n f32x4,
    // swizzled idx, two column-half passes), coalesced c/h read+write.
    auto epi = [&](f32x4 (&acc)[4][4], int colbase) {
#pragma unroll
        for (int im = 0; im < 4; ++im)
#pragma unroll
            for (int jn = 0; jn < 4; ++jn) {
                const int rr  = row0 + mwb + im * 16 + quad * 4;
                const int col = colbase + nwb + jn * 16 + l15;
                const int n = rr >> 2;
                bf16x4 xg4 = *(const bf16x4*)(xg + ((size_t)n * NXc + (col + xo)) * 4);
                acc[im][jn][0] += (float)xg4[0];
                acc[im][jn][1] += (float)xg4[1];
                acc[im][jn][2] += (float)xg4[2];
                acc[im][jn][3] += (float)xg4[3];
            }
#pragma unroll
        for (int pass = 0; pass < 2; ++pass) {
            if ((wave & 1) == pass) {            // this wave's cols in this half
                const int nw = (wave >> 1) * 16;
#pragma unroll
                for (int im = 0; im < 4; ++im)
#pragma unroll
                    for (int jn = 0; jn < 4; ++jn) {
                        const int n_l = nw + im * 4 + quad;
                        const int c_l = jn * 16 + l15;
                        sG[c_l * 32 + (n_l ^ (c_l & 7))] = acc[im][jn];
                    }
            }
            __syncthreads();
            {
                const int c_l  = tid >> 2;       // [0,64)
                const int nb   = (tid & 3) * 8;  // [0,32) step 8
                const int colg = colbase + pass * 64 + c_l;
                const fp16_t* crp = p.c_r + (size_t)(colg + cro) * Hh + nbase + nb;
                fp16x8 c8 = *(const fp16x8*)crp; // 16B coalesced
                bf16x8 h8o; fp16x8 c8o;
#pragma unroll
                for (int j = 0; j < 8; ++j) {
                    f32x4 g = sG[c_l * 32 + ((nb + j) ^ (c_l & 7))];
                    float c2 = sigm(g[1]) * (float)c8[j] + sigm(g[0]) * tanh_f(g[2]);
                    float h2 = sigm(g[3]) * tanh_f(c2);
                    c8o[j] = (fp16_t)c2;
                    h8o[j] = (bf16_t)h2;
                }
                *(fp16x8*)(p.c_w + (size_t)(colg + cwo) * Hh + nbase + nb) = c8o;
                *(bf16x8*)(p.h_w + (size_t)(colg + cwo) * Hh + nbase + nb) = h8o;
            }
            __syncthreads();                     // protect LDS before next writes
        }
    };
    epi(accL, colp * 256);
    epi(accR, colp * 256 + 128);
}

// ---------------------------------------------------------------------------
// Weight conversion: fp32 [4H,K] -> bf16 [4H,K] with row perm 4n+g <- g*H+n
// ---------------------------------------------------------------------------
__global__ void cvt_w(const float* __restrict__ a0, const float* __restrict__ a1,
                      const float* __restrict__ a2, const float* __restrict__ a3,
                      bf16_t* __restrict__ o0, bf16_t* __restrict__ o1,
                      bf16_t* __restrict__ o2, bf16_t* __restrict__ o3)
{
    int idx = blockIdx.x * 256 + threadIdx.x;
    int mat = idx >> 20;
    int r   = (idx >> 8) & 4095;
    int k4  = (idx & 255) * 4;
    int n = r >> 2, g = r & 3;
    const float* src = mat == 0 ? a0 : mat == 1 ? a1 : mat == 2 ? a2 : a3;
    bf16_t*      dst = mat == 0 ? o0 : mat == 1 ? o1 : mat == 2 ? o2 : o3;
    f32x4 v = *(const f32x4*)(src + (size_t)(g * Hh + n) * Kk + k4);
    bf16x4 o;
    o[0] = (bf16_t)v[0]; o[1] = (bf16_t)v[1]; o[2] = (bf16_t)v[2]; o[3] = (bf16_t)v[3];
    *(bf16x4*)(dst + (size_t)r * Kk + k4) = o;
}

__global__ void cvt_bias(const float* __restrict__ bih_r, const float* __restrict__ bhh_r,
                         const float* __restrict__ bih_u, const float* __restrict__ bhh_u,
                         float* __restrict__ br, float* __restrict__ bu)
{
    int r = blockIdx.x * 256 + threadIdx.x;
    int n = r >> 2, g = r & 3;
    int ir = g * Hh + n;
    br[r] = bih_r[ir] + bhh_r[ir];
    bu[r] = bih_u[ir] + bhh_u[ir];
}

// x [b*14+s][f] fp32 -> x_b [s*256+b][f] bf16
__global__ void cvt_x(const float* __restrict__ src, bf16_t* __restrict__ dst)
{
    int idx = blockIdx.x * 256 + threadIdx.x;
    int f4  = (idx & 255) * 4;
    int row = idx >> 8;
    int s = row % 14, b = row / 14;
    f32x4 v = *(const f32x4*)(src + (size_t)row * Kk + f4);
    bf16x4 o;
    o[0] = (bf16_t)v[0]; o[1] = (bf16_t)v[1]; o[2] = (bf16_t)v[2]; o[3] = (bf16_t)v[3];
    *(bf16x4*)(dst + (size_t)(s * 256 + b) * Kk + f4) = o;
}

__global__ void cast_f32_bf16(const float* __restrict__ src, bf16_t* __restrict__ dst, int n4)
{
    int i = blockIdx.x * 256 + threadIdx.x;
    if (i < n4) {
        f32x4 v = *(const f32x4*)(src + (size_t)i * 4);
        bf16x4 o;
        o[0] = (bf16_t)v[0]; o[1] = (bf16_t)v[1]; o[2] = (bf16_t)v[2]; o[3] = (bf16_t)v[3];
        *(bf16x4*)(dst + (size_t)i * 4) = o;
    }
}

// ---------------------------------------------------------------------------
extern "C" void kernel_launch(void* const* d_in, const int* in_sizes, int n_in,
                              void* d_out, int out_size, void* d_ws, size_t ws_size,
                              hipStream_t stream)
{
    const float* x_in  = (const float*)d_in[0];
    const float* Wih_r = (const float*)d_in[1];
    const float* Whh_r = (const float*)d_in[2];
    const float* bih_r = (const float*)d_in[3];
    const float* bhh_r = (const float*)d_in[4];
    const float* Wih_u = (const float*)d_in[5];
    const float* Whh_u = (const float*)d_in[6];
    const float* bih_u = (const float*)d_in[7];
    const float* bhh_u = (const float*)d_in[8];
    const float* Wc    = (const float*)d_in[9];
    const float* bc    = (const float*)d_in[10];
    float* out = (float*)d_out;

    char* ws = (char*)d_ws;
    size_t off = 0;
    auto alloc = [&](size_t bytes) -> char* {
        char* p = ws + off;
        off += (bytes + 255) & ~(size_t)255;
        return p;
    };

    const size_t BH = (size_t)Bb * Hh;                 // 262144 elems
    bf16_t* w_ih2  = (bf16_t*)alloc((size_t)8192 * Kk * 2);  // [roll | unroll]
    bf16_t* w_hhr  = (bf16_t*)alloc((size_t)4096 * Kk * 2);
    bf16_t* w_hhu  = (bf16_t*)alloc((size_t)4096 * Kk * 2);
    bf16_t* wc_b   = (bf16_t*)alloc((size_t)Cc * Kk * 2);
    bf16_t* x_b    = (bf16_t*)alloc((size_t)NXc * Kk * 2);
    float*  bias2  = (float*)alloc(8192 * 4);
    bf16_t* XG2    = (bf16_t*)alloc((size_t)2048 * NXc * 4 * 2);
    bf16_t* P0     = (bf16_t*)alloc((size_t)Ss * BH * 2);
    bf16_t* P1     = (bf16_t*)alloc((size_t)Ss * BH * 2);
    fp16_t* Cp0    = (fp16_t*)alloc((size_t)Ss * BH * 2);
    fp16_t* Cp1    = (fp16_t*)alloc((size_t)Ss * BH * 2);
    bf16_t* h0     = (bf16_t*)alloc(BH * 2);
    fp16_t* c0     = (fp16_t*)alloc(BH * 2);

    bf16_t* XGr = XG2;
    bf16_t* XGu = XG2 + (size_t)1024 * NXc * 4;
    bf16_t* P[2] = {P0, P1};
    fp16_t* Cp[2] = {Cp0, Cp1};

    hipMemsetAsync(h0, 0, BH * 2, stream);
    hipMemsetAsync(c0, 0, BH * 2, stream);

    // conversions
    cvt_w<<<16384, 256, 0, stream>>>(Wih_r, Whh_r, Wih_u, Whh_u,
                                     w_ih2, w_hhr, w_ih2 + (size_t)4096 * Kk, w_hhu);
    cvt_bias<<<16, 256, 0, stream>>>(bih_r, bhh_r, bih_u, bhh_u, bias2, bias2 + 4096);
    cvt_x<<<3584, 256, 0, stream>>>(x_in, x_b);
    cast_f32_bf16<<<(Cc * Kk / 4 + 255) / 256, 256, 0, stream>>>(Wc, wc_b, Cc * Kk / 4);

    // xproj chunk schedule (chunk = one col-pair = 32 blocks):
    // chunk c<14 = roll cols c*256 (id c); c>=14 = unroll cols (c-14)*256.
    // Deadlines: r_j in dispatch <= j, u_j in dispatch <= j+1. r0 in prologue.
    static const int xp_sched[2][15] = {
        { 1, 14,  2, 15,  3, 16,  4, 17,  5, 18,  6, 19,  7, 20,  8},  // s1
        {21,  9, 22, 10, 23, 11, 24, 12, 25, 13, 26, 27, -1, -1, -1},  // s2
    };
    static const int xp_n[2] = {15, 12};

    // prologue: chunk r0 only (needed by step 1's roll epilogue)
    {
        StepArgs p{};
        p.Au = w_hhu; p.Ar = w_hhr; p.Bh = h0;
        p.xg_u = XGu; p.xg_r = XGr;
        p.c_r = c0; p.c_w = Cp[0]; p.h_w = P[0];
        p.Wih = w_ih2; p.Xb = x_b; p.bias2 = bias2; p.XG2 = XG2;
        p.UCP = 0; p.b_off = 0; p.xg_off = 0; p.cr_off = 0; p.cw_off = 0;
        p.CP = 0; p.cppg = 1;
        p.nRec = 0;
        p.xp[0] = 0;
        for (int i = 1; i < 15; ++i) p.xp[i] = -1;
        lstm_step<<<32, 256, 0, stream>>>(p);
    }

    // skewed recurrent schedule: 16 global steps, roll + lockstep unroll merged,
    // with xproj filler blocks in steps 1-2
    for (int k = 1; k <= 16; ++k) {
        int a = (k - 1 < 14) ? (k - 1) : 14;
        int rollk = (k <= 14) ? 1 : 0;
        StepArgs p{};
        p.Au = w_hhu;  p.Ar = w_hhr;
        p.Bh = (k == 1) ? h0 : P[(k - 1) & 1];
        p.xg_u = XGu;  p.xg_r = XGr;
        p.c_r = (k == 1) ? c0 : Cp[(k - 1) & 1];
        p.c_w = Cp[k & 1];
        p.h_w = P[k & 1];
        p.Wih = w_ih2; p.Xb = x_b; p.bias2 = bias2; p.XG2 = XG2;
        p.UCP = a;
        p.b_off  = (k >= 2) ? (k - 2) * 256 : 0;
        p.xg_off = (k - 1) * 256;
        p.cr_off = (k >= 2) ? (k - 2) * 256 : 0;
        p.cw_off = (k - 1) * 256;
        p.CP   = a + rollk;
        p.cppg = (p.CP + 3) >> 2;
        p.nRec = 8 * 16 * p.cppg;
        int nxp = (k <= 2) ? xp_n[k - 1] : 0;
        for (int i = 0; i < 15; ++i)
            p.xp[i] = (k <= 2 && i < nxp) ? xp_sched[k - 1][i] : -1;
        lstm_step<<<p.nRec + nxp * 32, 256, 0, stream>>>(p);
    }

    // classifier: A = final h states in P[0] (A-row remap), out [3584,2513]
    // 28 row-blocks x 10 col-pairs; RG=2 x CG=4 XCD groups
    gemm_bt<2><<<336, 256, 0, stream>>>(P[0], wc_b, Cc, 14, 3, 4, 10,
                                        bc, nullptr, out);
}

// Round 7
// 815.743 us; speedup vs baseline: 1.0291x; 1.0291x over previous
//
#include <hip/hip_runtime.h>
#include <hip/hip_bf16.h>

#define GLOBAL_AS __attribute__((address_space(1)))
#define LDS_AS    __attribute__((address_space(3)))

typedef __bf16 bf16_t;
typedef __bf16 bf16x8 __attribute__((ext_vector_type(8)));
typedef __bf16 bf16x4 __attribute__((ext_vector_type(4)));
typedef float  f32x4  __attribute__((ext_vector_type(4)));
typedef _Float16 fp16_t;
typedef _Float16 fp16x8 __attribute__((ext_vector_type(8)));

static constexpr int Bb = 256;    // batch
static constexpr int Ss = 14;     // seq
static constexpr int Hh = 1024;   // hidden
static constexpr int Cc = 2513;   // classes
static constexpr int NXc = 3584;  // B*S
static constexpr int Kk = 1024;   // K (== F == H)

__device__ __forceinline__ float sigm(float x)   { return 1.0f / (1.0f + __expf(-x)); }
__device__ __forceinline__ float tanh_f(float x) { return 2.0f / (1.0f + __expf(-2.0f * x)) - 1.0f; }

// ---------------------------------------------------------------------------
// 128x128-tile bf16 GEMM (r3-verified, 256 threads): C = A @ B^T, K=1024,
// BK=64, stage->sync->compute->sync. Used for the classifier only.
// EPI 2: A rows remapped row -> (row%14)*256 + row/14; add col-bias; f32 out.
// ---------------------------------------------------------------------------
template<int EPI>
__global__ __launch_bounds__(256, 2)
void gemm_bt(const bf16_t* __restrict__ A, const bf16_t* __restrict__ Bm,
             int N, int rpg, int cpg, int CG, int CB,
             const float* __restrict__ e_bias,
             bf16_t* __restrict__ xg_bf,
             float* __restrict__ fout)
{
    const int lin = blockIdx.x;
    const int xcd = lin & 7;
    const int per = lin >> 3;
    const int rg = xcd / CG, cg = xcd % CG;
    const int rb = rg * rpg + per % rpg;
    const int cb = cg * cpg + per / rpg;
    if (cb >= CB) return;

    __shared__ char smem[32768];                // A tile 16K | B tile 16K
    LDS_AS char* sA = (LDS_AS char*)smem;
    LDS_AS char* sB = sA + 16384;

    const int tid  = threadIdx.x;
    const int lane = tid & 63;
    const int wave = tid >> 6;
    const int row0 = rb * 128;
    const int col0 = cb * 128;
    const int mwb  = (wave >> 1) * 64;
    const int nwb  = (wave & 1) * 64;
    const int quad = lane >> 4;
    const int l15  = lane & 15;

    f32x4 acc[4][4] = {};

    for (int kb = 0; kb < Kk; kb += 64) {
#pragma unroll
        for (int it = 0; it < 4; ++it) {
            int c  = it * 256 + tid;
            int m  = c >> 3;
            int kq = (c & 7) ^ (m & 7);
            size_t arow;
            if (EPI == 2) {                      // A-row remap: b*14+s -> s*256+b
                int row = row0 + m;
                int bb = row / 14;
                int ss = row - bb * 14;
                arow = (size_t)(ss * 256 + bb);
            } else {
                arow = (size_t)(row0 + m);
            }
            const bf16_t* ga = A + arow * Kk + kb + kq * 8;
            int nr = col0 + m;
            if (EPI == 2) { if (nr >= N) nr = 0; }
            const bf16_t* gb = Bm + (size_t)nr * Kk + kb + kq * 8;
            LDS_AS char* la = sA + (size_t)(it * 256 + (tid & 192)) * 16;
            LDS_AS char* lb = sB + (size_t)(it * 256 + (tid & 192)) * 16;
            __builtin_amdgcn_global_load_lds((const GLOBAL_AS void*)ga, (LDS_AS void*)la, 16, 0, 0);
            __builtin_amdgcn_global_load_lds((const GLOBAL_AS void*)gb, (LDS_AS void*)lb, 16, 0, 0);
        }
        __syncthreads();

#pragma unroll
        for (int kt = 0; kt < 2; ++kt) {
            bf16x8 af[4], bfr[4];
            const int kq = kt * 4 + quad;
#pragma unroll
            for (int i = 0; i < 4; ++i) {
                int ml = mwb + i * 16 + l15;
                af[i]  = *(const LDS_AS bf16x8*)(sA + (size_t)(ml * 8 + (kq ^ (ml & 7))) * 16);
                int nl = nwb + i * 16 + l15;
                bfr[i] = *(const LDS_AS bf16x8*)(sB + (size_t)(nl * 8 + (kq ^ (nl & 7))) * 16);
            }
#pragma unroll
            for (int i = 0; i < 4; ++i)
#pragma unroll
                for (int j = 0; j < 4; ++j)
                    acc[i][j] = __builtin_amdgcn_mfma_f32_16x16x32_bf16(af[i], bfr[j], acc[i][j], 0, 0, 0);
        }
        __syncthreads();
    }

#pragma unroll
    for (int im = 0; im < 4; ++im) {
#pragma unroll
        for (int jn = 0; jn < 4; ++jn) {
            const int rr  = row0 + mwb + im * 16 + quad * 4;
            const int col = col0 + nwb + jn * 16 + l15;
            f32x4 v = acc[im][jn];
            if (EPI == 0) {
                const int n = rr >> 2;
                f32x4 bi = *(const f32x4*)(e_bias + n * 4);
                bf16x4 o;
                o[0] = (bf16_t)(v[0] + bi[0]); o[1] = (bf16_t)(v[1] + bi[1]);
                o[2] = (bf16_t)(v[2] + bi[2]); o[3] = (bf16_t)(v[3] + bi[3]);
                *(bf16x4*)(xg_bf + ((size_t)n * NXc + col) * 4) = o;
            } else {
                if (col < N) {
                    float bi = e_bias[col];
#pragma unroll
                    for (int g = 0; g < 4; ++g)
                        fout[(size_t)(rr + g) * N + col] = v[g] + bi;
                }
            }
        }
    }
}

// ---------------------------------------------------------------------------
// Merged recurrent step, 2-WAVE (128-thread) blocks, 128x128 tile:
// each wave owns 64 rows x 128 cols -> acc[4][8], 12 ds_read_b128 per 32
// MFMA (reads:MFMA 0.375 vs 0.5 before) and LDS stays 32KB -> up to 5
// blocks/CU co-resident (r1 evidence: MfmaUtil tracks resident blocks).
// Same r3-verified skeleton: stage -> sync -> compute -> sync; 8-slot XOR
// swizzle on both sides; gate epilogue via swizzled LDS bounce.
//   recurrent region (blocks < nRec, XCD 2D map):
//     unroll col-blocks [0, UCB): A=Au ; roll col-blocks [UCB, CB): A=Ar
//   xproj filler (blocks >= nRec): 128^2 tiles of XG = W_ih @ x^T + bias;
//     chunk c<14 = roll cols c*256, c>=14 = unroll cols (c-14)*256;
//     chunk = 64 blocks. All 27 remaining chunks packed into steps 1-2
//     (1024/960-block grids = the high-residency regime).
// ---------------------------------------------------------------------------
struct StepArgs {
    const bf16_t* Au;     // unroll weight [4096,1024] perm-rows
    const bf16_t* Ar;     // roll weight
    const bf16_t* Bh;     // h read base (P[(k-1)&1]; h0 for k==1)
    const bf16_t* xg_u;   // XGu [n][col][4]
    const bf16_t* xg_r;   // XGr
    const fp16_t* c_r;    // c read base
    fp16_t*       c_w;    // c write base
    bf16_t*       h_w;    // h write base
    const bf16_t* Wih;    // [8192,1024] perm-rows (roll | unroll)
    const bf16_t* Xb;     // x_b [s*256+b][1024]
    const float*  bias2;  // [8192] fused biases (roll | unroll)
    bf16_t*       XG2;    // XG output base
    int UCB;              // unroll col-blocks (2a)
    int b_off;            // roll B col offset   = (k-2)*256
    int xg_off;           // roll xg col offset  = (k-1)*256
    int cr_off;           // roll c-read offset  = (k-2)*256
    int cw_off;           // roll c/h-write off  = (k-1)*256
    int CB, cpg;          // total col-blocks, col-blocks per XCD group
    int nRec;             // blocks below this: recurrent region
    int xp[14];           // xproj chunk ids for this step
};

__global__ __launch_bounds__(128, 2)
void lstm_step(StepArgs p)
{
    const int tid  = threadIdx.x;
    const int lane = tid & 63;
    const int wave = tid >> 6;          // 0..1; wave rows = [wave*64, wave*64+64)
    const int quad = lane >> 4;
    const int l15  = lane & 15;

    __shared__ char smem[32768];        // A 16K | B 16K; epi bounce reuses 32K
    LDS_AS char* sA = (LDS_AS char*)smem;
    LDS_AS char* sB = sA + 16384;

    const bf16_t* A;
    const bf16_t* Bbase;
    int row0, bcol0;
    bool isxp;
    bool roll = false;
    int  colb = 0;

    if ((int)blockIdx.x >= p.nRec) {
        isxp = true;
        const int idx = (int)blockIdx.x - p.nRec;
        const int c   = p.xp[idx >> 6];
        const int isu = (c >= 14) ? 1 : 0;
        const int j   = c - isu * 14;
        const int rb  = idx & 31;
        const int cbl = (idx >> 5) & 1;
        row0  = isu * 4096 + rb * 128;      // absolute row in [0,8192)
        bcol0 = j * 256 + cbl * 128;        // absolute col in [0,3584)
        A     = p.Wih;
        Bbase = p.Xb;
    } else {
        isxp = false;
        const int lin = blockIdx.x;
        const int xcd = lin & 7;
        const int per = lin >> 3;
        const int rb = (xcd >> 2) * 16 + (per & 15);
        const int cb = (xcd & 3) * p.cpg + (per >> 4);
        if (cb >= p.CB) return;
        roll = (cb >= p.UCB);
        colb = roll ? (cb - p.UCB) : cb;
        A     = roll ? p.Ar : p.Au;
        Bbase = p.Bh;
        row0  = rb * 128;
        bcol0 = colb * 128 + (roll ? p.b_off : 0);
    }

    f32x4 acc[4][8] = {};

    for (int kb = 0; kb < Kk; kb += 64) {
#pragma unroll
        for (int it = 0; it < 8; ++it) {
            int c  = it * 128 + tid;
            int m  = c >> 3;                 // row 0..127
            int kq = (c & 7) ^ (m & 7);      // pre-swizzled global chunk
            const bf16_t* ga = A     + (size_t)(row0  + m) * Kk + kb + kq * 8;
            const bf16_t* gb = Bbase + (size_t)(bcol0 + m) * Kk + kb + kq * 8;
            LDS_AS char* la = sA + (size_t)(it * 128 + (tid & 64)) * 16;
            LDS_AS char* lb = sB + (size_t)(it * 128 + (tid & 64)) * 16;
            __builtin_amdgcn_global_load_lds((const GLOBAL_AS void*)ga, (LDS_AS void*)la, 16, 0, 0);
            __builtin_amdgcn_global_load_lds((const GLOBAL_AS void*)gb, (LDS_AS void*)lb, 16, 0, 0);
        }
        __syncthreads();

#pragma unroll
        for (int kt = 0; kt < 2; ++kt) {
            bf16x8 af[4], bfr[8];
            const int kq = kt * 4 + quad;
#pragma unroll
            for (int i = 0; i < 4; ++i) {
                int ml = wave * 64 + i * 16 + l15;
                af[i]  = *(const LDS_AS bf16x8*)(sA + (size_t)(ml * 8 + (kq ^ (ml & 7))) * 16);
            }
#pragma unroll
            for (int j = 0; j < 8; ++j) {
                int nl = j * 16 + l15;
                bfr[j] = *(const LDS_AS bf16x8*)(sB + (size_t)(nl * 8 + (kq ^ (nl & 7))) * 16);
            }
#pragma unroll
            for (int i = 0; i < 4; ++i)
#pragma unroll
                for (int j = 0; j < 8; ++j)
                    acc[i][j] = __builtin_amdgcn_mfma_f32_16x16x32_bf16(af[i], bfr[j], acc[i][j], 0, 0, 0);
        }
        __syncthreads();
    }

    if (isxp) {
        // input-projection epilogue: add row-bias, store bf16x4 to XG[n][col][4]
#pragma unroll
        for (int im = 0; im < 4; ++im) {
#pragma unroll
            for (int jn = 0; jn < 8; ++jn) {
                const int rr  = row0 + wave * 64 + im * 16 + quad * 4;
                const int col = bcol0 + jn * 16 + l15;
                f32x4 v = acc[im][jn];
                const int n = rr >> 2;
                f32x4 bi = *(const f32x4*)(p.bias2 + n * 4);
                bf16x4 o;
                o[0] = (bf16_t)(v[0] + bi[0]); o[1] = (bf16_t)(v[1] + bi[1]);
                o[2] = (bf16_t)(v[2] + bi[2]); o[3] = (bf16_t)(v[3] + bi[3]);
                *(bf16x4*)(p.XG2 + ((size_t)n * NXc + col) * 4) = o;
            }
        }
        return;
    }

    const bf16_t* xg = roll ? p.xg_r : p.xg_u;
    const int xo  = roll ? p.xg_off : 0;
    const int cro = roll ? p.cr_off : 0;
    const int cwo = roll ? p.cw_off : 0;
    const int nbase = row0 >> 2;                 // 32-aligned

    // fold xg into acc (coalesced bf16x4 loads)
#pragma unroll
    for (int im = 0; im < 4; ++im)
#pragma unroll
        for (int jn = 0; jn < 8; ++jn) {
            const int rr  = row0 + wave * 64 + im * 16 + quad * 4;
            const int col = colb * 128 + jn * 16 + l15;
            const int n = rr >> 2;
            bf16x4 xg4 = *(const bf16x4*)(xg + ((size_t)n * NXc + (col + xo)) * 4);
            acc[im][jn][0] += (float)xg4[0];
            acc[im][jn][1] += (float)xg4[1];
            acc[im][jn][2] += (float)xg4[2];
            acc[im][jn][3] += (float)xg4[3];
        }

    // LDS bounce: 64 cols x 32 n of f32x4 gates (32KB), swizzled idx, two
    // column-half passes; K-loop ended with __syncthreads -> LDS free.
    LDS_AS f32x4* sG = (LDS_AS f32x4*)smem;

#pragma unroll
    for (int pass = 0; pass < 2; ++pass) {
#pragma unroll
        for (int im = 0; im < 4; ++im)
#pragma unroll
            for (int jj = 0; jj < 4; ++jj) {
                const int jn  = pass * 4 + jj;
                const int n_l = wave * 16 + im * 4 + quad;   // 0..31
                const int c_l = jj * 16 + l15;               // 0..63
                sG[c_l * 32 + (n_l ^ (c_l & 7))] = acc[im][jn];
            }
        __syncthreads();
#pragma unroll
        for (int rep = 0; rep < 2; ++rep) {
            const int c_l  = tid >> 1;                       // 0..63
            const int nb   = (tid & 1) * 8 + rep * 16;       // 0,8,16,24
            const int colg = colb * 128 + pass * 64 + c_l;
            const fp16_t* crp = p.c_r + (size_t)(colg + cro) * Hh + nbase + nb;
            fp16x8 c8 = *(const fp16x8*)crp;                 // 16B coalesced
            bf16x8 h8o; fp16x8 c8o;
#pragma unroll
            for (int j = 0; j < 8; ++j) {
                f32x4 g = sG[c_l * 32 + ((nb + j) ^ (c_l & 7))];
                float c2 = sigm(g[1]) * (float)c8[j] + sigm(g[0]) * tanh_f(g[2]);
                float h2 = sigm(g[3]) * tanh_f(c2);
                c8o[j] = (fp16_t)c2;
                h8o[j] = (bf16_t)h2;
            }
            *(fp16x8*)(p.c_w + (size_t)(colg + cwo) * Hh + nbase + nb) = c8o;
            *(bf16x8*)(p.h_w + (size_t)(colg + cwo) * Hh + nbase + nb) = h8o;
        }
        if (pass == 0) __syncthreads();          // protect LDS before pass-1 writes
    }
}

// ---------------------------------------------------------------------------
// Weight conversion: fp32 [4H,K] -> bf16 [4H,K] with row perm 4n+g <- g*H+n
// ---------------------------------------------------------------------------
__global__ void cvt_w(const float* __restrict__ a0, const float* __restrict__ a1,
                      const float* __restrict__ a2, const float* __restrict__ a3,
                      bf16_t* __restrict__ o0, bf16_t* __restrict__ o1,
                      bf16_t* __restrict__ o2, bf16_t* __restrict__ o3)
{
    int idx = blockIdx.x * 256 + threadIdx.x;
    int mat = idx >> 20;
    int r   = (idx >> 8) & 4095;
    int k4  = (idx & 255) * 4;
    int n = r >> 2, g = r & 3;
    const float* src = mat == 0 ? a0 : mat == 1 ? a1 : mat == 2 ? a2 : a3;
    bf16_t*      dst = mat == 0 ? o0 : mat == 1 ? o1 : mat == 2 ? o2 : o3;
    f32x4 v = *(const f32x4*)(src + (size_t)(g * Hh + n) * Kk + k4);
    bf16x4 o;
    o[0] = (bf16_t)v[0]; o[1] = (bf16_t)v[1]; o[2] = (bf16_t)v[2]; o[3] = (bf16_t)v[3];
    *(bf16x4*)(dst + (size_t)r * Kk + k4) = o;
}

__global__ void cvt_bias(const float* __restrict__ bih_r, const float* __restrict__ bhh_r,
                         const float* __restrict__ bih_u, const float* __restrict__ bhh_u,
                         float* __restrict__ br, float* __restrict__ bu)
{
    int r = blockIdx.x * 256 + threadIdx.x;
    int n = r >> 2, g = r & 3;
    int ir = g * Hh + n;
    br[r] = bih_r[ir] + bhh_r[ir];
    bu[r] = bih_u[ir] + bhh_u[ir];
}

// x [b*14+s][f] fp32 -> x_b [s*256+b][f] bf16
__global__ void cvt_x(const float* __restrict__ src, bf16_t* __restrict__ dst)
{
    int idx = blockIdx.x * 256 + threadIdx.x;
    int f4  = (idx & 255) * 4;
    int row = idx >> 8;
    int s = row % 14, b = row / 14;
    f32x4 v = *(const f32x4*)(src + (size_t)row * Kk + f4);
    bf16x4 o;
    o[0] = (bf16_t)v[0]; o[1] = (bf16_t)v[1]; o[2] = (bf16_t)v[2]; o[3] = (bf16_t)v[3];
    *(bf16x4*)(dst + (size_t)(s * 256 + b) * Kk + f4) = o;
}

__global__ void cast_f32_bf16(const float* __restrict__ src, bf16_t* __restrict__ dst, int n4)
{
    int i = blockIdx.x * 256 + threadIdx.x;
    if (i < n4) {
        f32x4 v = *(const f32x4*)(src + (size_t)i * 4);
        bf16x4 o;
        o[0] = (bf16_t)v[0]; o[1] = (bf16_t)v[1]; o[2] = (bf16_t)v[2]; o[3] = (bf16_t)v[3];
        *(bf16x4*)(dst + (size_t)i * 4) = o;
    }
}

// ---------------------------------------------------------------------------
extern "C" void kernel_launch(void* const* d_in, const int* in_sizes, int n_in,
                              void* d_out, int out_size, void* d_ws, size_t ws_size,
                              hipStream_t stream)
{
    const float* x_in  = (const float*)d_in[0];
    const float* Wih_r = (const float*)d_in[1];
    const float* Whh_r = (const float*)d_in[2];
    const float* bih_r = (const float*)d_in[3];
    const float* bhh_r = (const float*)d_in[4];
    const float* Wih_u = (const float*)d_in[5];
    const float* Whh_u = (const float*)d_in[6];
    const float* bih_u = (const float*)d_in[7];
    const float* bhh_u = (const float*)d_in[8];
    const float* Wc    = (const float*)d_in[9];
    const float* bc    = (const float*)d_in[10];
    float* out = (float*)d_out;

    char* ws = (char*)d_ws;
    size_t off = 0;
    auto alloc = [&](size_t bytes) -> char* {
        char* p = ws + off;
        off += (bytes + 255) & ~(size_t)255;
        return p;
    };

    const size_t BH = (size_t)Bb * Hh;                 // 262144 elems
    bf16_t* w_ih2  = (bf16_t*)alloc((size_t)8192 * Kk * 2);  // [roll | unroll]
    bf16_t* w_hhr  = (bf16_t*)alloc((size_t)4096 * Kk * 2);
    bf16_t* w_hhu  = (bf16_t*)alloc((size_t)4096 * Kk * 2);
    bf16_t* wc_b   = (bf16_t*)alloc((size_t)Cc * Kk * 2);
    bf16_t* x_b    = (bf16_t*)alloc((size_t)NXc * Kk * 2);
    float*  bias2  = (float*)alloc(8192 * 4);
    bf16_t* XG2    = (bf16_t*)alloc((size_t)2048 * NXc * 4 * 2);
    bf16_t* P0     = (bf16_t*)alloc((size_t)Ss * BH * 2);
    bf16_t* P1     = (bf16_t*)alloc((size_t)Ss * BH * 2);
    fp16_t* Cp0    = (fp16_t*)alloc((size_t)Ss * BH * 2);
    fp16_t* Cp1    = (fp16_t*)alloc((size_t)Ss * BH * 2);
    bf16_t* h0     = (bf16_t*)alloc(BH * 2);
    fp16_t* c0     = (fp16_t*)alloc(BH * 2);

    bf16_t* XGr = XG2;
    bf16_t* XGu = XG2 + (size_t)1024 * NXc * 4;
    bf16_t* P[2] = {P0, P1};
    fp16_t* Cp[2] = {Cp0, Cp1};

    hipMemsetAsync(h0, 0, BH * 2, stream);
    hipMemsetAsync(c0, 0, BH * 2, stream);

    // conversions
    cvt_w<<<16384, 256, 0, stream>>>(Wih_r, Whh_r, Wih_u, Whh_u,
                                     w_ih2, w_hhr, w_ih2 + (size_t)4096 * Kk, w_hhu);
    cvt_bias<<<16, 256, 0, stream>>>(bih_r, bhh_r, bih_u, bhh_u, bias2, bias2 + 4096);
    cvt_x<<<3584, 256, 0, stream>>>(x_in, x_b);
    cast_f32_bf16<<<(Cc * Kk / 4 + 255) / 256, 256, 0, stream>>>(Wc, wc_b, Cc * Kk / 4);

    // xproj chunk schedule (chunk = 64 blocks): c<14 = roll cols c*256,
    // c>=14 = unroll cols (c-14)*256. Deadlines: r_j <= step j, u_j <= step
    // j+1; all met with margin. Steps 1-2 packed to 1024/960 blocks (4/CU).
    static const int xp_sched[2][14] = {
        { 1, 14,  2, 15,  3, 16,  4, 17,  5, 18,  6, 19,  7, 20},  // r1-r7,u0-u6
        { 8, 21,  9, 22, 10, 23, 11, 24, 12, 25, 13, 26, 27, -1},  // r8-r13,u7-u13
    };
    static const int xp_n[2] = {14, 13};

    // prologue: chunk r0 only (needed by step 1's roll epilogue)
    {
        StepArgs p{};
        p.Au = w_hhu; p.Ar = w_hhr; p.Bh = h0;
        p.xg_u = XGu; p.xg_r = XGr;
        p.c_r = c0; p.c_w = Cp[0]; p.h_w = P[0];
        p.Wih = w_ih2; p.Xb = x_b; p.bias2 = bias2; p.XG2 = XG2;
        p.UCB = 0; p.b_off = 0; p.xg_off = 0; p.cr_off = 0; p.cw_off = 0;
        p.CB = 0; p.cpg = 1;
        p.nRec = 0;
        p.xp[0] = 0;
        for (int i = 1; i < 14; ++i) p.xp[i] = -1;
        lstm_step<<<64, 128, 0, stream>>>(p);
    }

    // skewed recurrent schedule: 16 global steps, roll + lockstep unroll
    // merged, xproj filler in steps 1-2
    for (int k = 1; k <= 16; ++k) {
        int a = (k - 1 < 14) ? (k - 1) : 14;
        int rollk = (k <= 14) ? 1 : 0;
        StepArgs p{};
        p.Au = w_hhu;  p.Ar = w_hhr;
        p.Bh = (k == 1) ? h0 : P[(k - 1) & 1];
        p.xg_u = XGu;  p.xg_r = XGr;
        p.c_r = (k == 1) ? c0 : Cp[(k - 1) & 1];
        p.c_w = Cp[k & 1];
        p.h_w = P[k & 1];
        p.Wih = w_ih2; p.Xb = x_b; p.bias2 = bias2; p.XG2 = XG2;
        p.UCB = 2 * a;
        p.b_off  = (k >= 2) ? (k - 2) * 256 : 0;
        p.xg_off = (k - 1) * 256;
        p.cr_off = (k >= 2) ? (k - 2) * 256 : 0;
        p.cw_off = (k - 1) * 256;
        p.CB  = p.UCB + 2 * rollk;
        p.cpg = (p.CB + 3) >> 2;
        p.nRec = 8 * 16 * p.cpg;
        int nxp = (k <= 2) ? xp_n[k - 1] : 0;
        for (int i = 0; i < 14; ++i)
            p.xp[i] = (k <= 2 && i < nxp) ? xp_sched[k - 1][i] : -1;
        lstm_step<<<p.nRec + nxp * 64, 128, 0, stream>>>(p);
    }

    // classifier: A = final h states in P[0] (A-row remap), out [3584,2513]
    gemm_bt<2><<<560, 256, 0, stream>>>(P[0], wc_b, Cc, 14, 5, 4, 20,
                                        bc, nullptr, out);
}

// Round 8
// 700.015 us; speedup vs baseline: 1.1993x; 1.1653x over previous
//
#include <hip/hip_runtime.h>
#include <hip/hip_bf16.h>

#define GLOBAL_AS __attribute__((address_space(1)))
#define LDS_AS    __attribute__((address_space(3)))

typedef __bf16 bf16_t;
typedef __bf16 bf16x8 __attribute__((ext_vector_type(8)));
typedef __bf16 bf16x4 __attribute__((ext_vector_type(4)));
typedef float  f32x4  __attribute__((ext_vector_type(4)));
typedef _Float16 fp16_t;
typedef _Float16 fp16x8 __attribute__((ext_vector_type(8)));

static constexpr int Bb = 256;    // batch
static constexpr int Ss = 14;     // seq
static constexpr int Hh = 1024;   // hidden
static constexpr int Cc = 2513;   // classes
static constexpr int NXc = 3584;  // B*S
static constexpr int Kk = 1024;   // K (== F == H)

__device__ __forceinline__ float sigm(float x)   { return 1.0f / (1.0f + __expf(-x)); }
__device__ __forceinline__ float tanh_f(float x) { return 2.0f / (1.0f + __expf(-2.0f * x)) - 1.0f; }

// ---------------------------------------------------------------------------
// 128x128-tile bf16 GEMM (r3-verified): C = A @ B^T, K=1024, BK=64,
// stage -> sync -> compute -> sync. Occupancy model (r1-r7 fit):
// MfmaUtil_cap = waves/CU * 620cyc / iter-window; this 4-wave/32KB shape is
// the family optimum — do not trade LDS or waves for pipeline depth.
// EPI 2: classifier — A rows remapped row -> (row%14)*256 + row/14; add
//        col-bias; fp32 store.
// ---------------------------------------------------------------------------
template<int EPI>
__global__ __launch_bounds__(256, 2)
void gemm_bt(const bf16_t* __restrict__ A, const bf16_t* __restrict__ Bm,
             int N, int rpg, int cpg, int CG, int CB,
             const float* __restrict__ e_bias,
             bf16_t* __restrict__ xg_bf,
             float* __restrict__ fout)
{
    const int lin = blockIdx.x;
    const int xcd = lin & 7;
    const int per = lin >> 3;
    const int rg = xcd / CG, cg = xcd % CG;
    const int rb = rg * rpg + per % rpg;
    const int cb = cg * cpg + per / rpg;
    if (cb >= CB) return;

    __shared__ char smem[32768];                // A tile 16K | B tile 16K
    LDS_AS char* sA = (LDS_AS char*)smem;
    LDS_AS char* sB = sA + 16384;

    const int tid  = threadIdx.x;
    const int lane = tid & 63;
    const int wave = tid >> 6;
    const int row0 = rb * 128;
    const int col0 = cb * 128;
    const int mwb  = (wave >> 1) * 64;
    const int nwb  = (wave & 1) * 64;
    const int quad = lane >> 4;
    const int l15  = lane & 15;

    f32x4 acc[4][4] = {};

    for (int kb = 0; kb < Kk; kb += 64) {
#pragma unroll
        for (int it = 0; it < 4; ++it) {
            int c  = it * 256 + tid;
            int m  = c >> 3;
            int kq = (c & 7) ^ (m & 7);
            size_t arow;
            if (EPI == 2) {                      // A-row remap: b*14+s -> s*256+b
                int row = row0 + m;
                int bb = row / 14;
                int ss = row - bb * 14;
                arow = (size_t)(ss * 256 + bb);
            } else {
                arow = (size_t)(row0 + m);
            }
            const bf16_t* ga = A + arow * Kk + kb + kq * 8;
            int nr = col0 + m;
            if (EPI == 2) { if (nr >= N) nr = 0; }
            const bf16_t* gb = Bm + (size_t)nr * Kk + kb + kq * 8;
            LDS_AS char* la = sA + (size_t)(it * 256 + (tid & 192)) * 16;
            LDS_AS char* lb = sB + (size_t)(it * 256 + (tid & 192)) * 16;
            __builtin_amdgcn_global_load_lds((const GLOBAL_AS void*)ga, (LDS_AS void*)la, 16, 0, 0);
            __builtin_amdgcn_global_load_lds((const GLOBAL_AS void*)gb, (LDS_AS void*)lb, 16, 0, 0);
        }
        __syncthreads();

#pragma unroll
        for (int kt = 0; kt < 2; ++kt) {
            bf16x8 af[4], bfr[4];
            const int kq = kt * 4 + quad;
#pragma unroll
            for (int i = 0; i < 4; ++i) {
                int ml = mwb + i * 16 + l15;
                af[i]  = *(const LDS_AS bf16x8*)(sA + (size_t)(ml * 8 + (kq ^ (ml & 7))) * 16);
                int nl = nwb + i * 16 + l15;
                bfr[i] = *(const LDS_AS bf16x8*)(sB + (size_t)(nl * 8 + (kq ^ (nl & 7))) * 16);
            }
#pragma unroll
            for (int i = 0; i < 4; ++i)
#pragma unroll
                for (int j = 0; j < 4; ++j)
                    acc[i][j] = __builtin_amdgcn_mfma_f32_16x16x32_bf16(af[i], bfr[j], acc[i][j], 0, 0, 0);
        }
        __syncthreads();
    }

#pragma unroll
    for (int im = 0; im < 4; ++im) {
#pragma unroll
        for (int jn = 0; jn < 4; ++jn) {
            const int rr  = row0 + mwb + im * 16 + quad * 4;
            const int col = col0 + nwb + jn * 16 + l15;
            f32x4 v = acc[im][jn];
            if (EPI == 0) {
                const int n = rr >> 2;
                f32x4 bi = *(const f32x4*)(e_bias + n * 4);
                bf16x4 o;
                o[0] = (bf16_t)(v[0] + bi[0]); o[1] = (bf16_t)(v[1] + bi[1]);
                o[2] = (bf16_t)(v[2] + bi[2]); o[3] = (bf16_t)(v[3] + bi[3]);
                *(bf16x4*)(xg_bf + ((size_t)n * NXc + col) * 4) = o;
            } else {
                if (col < N) {
                    float bi = e_bias[col];
#pragma unroll
                    for (int g = 0; g < 4; ++g)
                        fout[(size_t)(rr + g) * N + col] = v[g] + bi;
                }
            }
        }
    }
}

// ---------------------------------------------------------------------------
// Merged recurrent step (r3-verified, skewed schedule, global step k):
//   recurrent region (blocks < nRec, XCD 2D map):
//     unroll col-blocks [0, UCB): A=Au, advance t<=k-2 lockstep
//     roll col-blocks  [UCB, CB): A=Ar, compute hs[k-1]
//   xproj filler blocks (blocks >= nRec): 128^2 tiles of the input-projection
//     GEMM, scheduled into the capacity-underfull early steps.
// Epilogue (recurrent): gates (+xg) bounced through a swizzled LDS tile so
// c-read / h,c-writes are fully coalesced 16B vector ops.
// h ping-pong bf16, c ping-pong fp16.
// ---------------------------------------------------------------------------
struct StepArgs {
    const bf16_t* Au;     // unroll weight [4096,1024] perm-rows
    const bf16_t* Ar;     // roll weight
    const bf16_t* Bh;     // h read base (P[(k-1)&1]; h0 for k==1)
    const bf16_t* xg_u;   // XGu [n][col][4]
    const bf16_t* xg_r;   // XGr
    const fp16_t* c_r;    // c read base
    fp16_t*       c_w;    // c write base
    bf16_t*       h_w;    // h write base
    const bf16_t* Wih;    // [8192,1024] perm-rows (roll | unroll)
    const bf16_t* Xb;     // x_b [s*256+b][1024]
    const float*  bias2;  // [8192] fused biases (roll | unroll)
    bf16_t*       XG2;    // XG output base (n absolute 0..2048)
    int UCB;              // unroll col-blocks (2a)
    int b_off;            // roll B col offset   = (k-2)*256
    int xg_off;           // roll xg col offset  = (k-1)*256
    int cr_off;           // roll c-read offset  = (k-2)*256
    int cw_off;           // roll c/h-write off  = (k-1)*256
    int CB, cpg;          // total col-blocks, cols per XCD group (CG=4,RG=2)
    int nRec;             // blocks below this: recurrent region
    int xp[7];            // xproj chunk ids for this step (grid sized to count)
};

__global__ __launch_bounds__(256, 2)
void lstm_step(StepArgs p)
{
    const int tid  = threadIdx.x;
    const int lane = tid & 63;
    const int wave = tid >> 6;
    const int mwb  = (wave >> 1) * 64;
    const int nwb  = (wave & 1) * 64;
    const int quad = lane >> 4;
    const int l15  = lane & 15;

    __shared__ char smem[32768];
    LDS_AS char* sA = (LDS_AS char*)smem;
    LDS_AS char* sB = sA + 16384;

    const bf16_t* A;
    const bf16_t* Bbase;
    int row0, bcol0;
    bool isxp;
    bool roll = false;
    int  colb = 0;

    if ((int)blockIdx.x >= p.nRec) {
        isxp = true;
        const int idx = (int)blockIdx.x - p.nRec;
        const int c   = p.xp[idx >> 6];
        const int isu = (c >= 14) ? 1 : 0;
        const int j   = c - isu * 14;
        const int rb  = idx & 31;
        const int cbl = (idx >> 5) & 1;
        row0  = isu * 4096 + rb * 128;      // absolute row in [0,8192)
        bcol0 = j * 256 + cbl * 128;        // absolute col in [0,3584)
        A     = p.Wih;
        Bbase = p.Xb;
    } else {
        isxp = false;
        const int lin = blockIdx.x;
        const int xcd = lin & 7;
        const int per = lin >> 3;
        const int rb = (xcd >> 2) * 16 + (per & 15);
        const int cb = (xcd & 3) * p.cpg + (per >> 4);
        if (cb >= p.CB) return;
        roll = (cb >= p.UCB);
        colb = roll ? (cb - p.UCB) : cb;
        A     = roll ? p.Ar : p.Au;
        Bbase = p.Bh;
        row0  = rb * 128;
        bcol0 = colb * 128 + (roll ? p.b_off : 0);
    }

    f32x4 acc[4][4] = {};

    for (int kb = 0; kb < Kk; kb += 64) {
#pragma unroll
        for (int it = 0; it < 4; ++it) {
            int c  = it * 256 + tid;
            int m  = c >> 3;
            int kq = (c & 7) ^ (m & 7);
            const bf16_t* ga = A     + (size_t)(row0  + m) * Kk + kb + kq * 8;
            const bf16_t* gb = Bbase + (size_t)(bcol0 + m) * Kk + kb + kq * 8;
            LDS_AS char* la = sA + (size_t)(it * 256 + (tid & 192)) * 16;
            LDS_AS char* lb = sB + (size_t)(it * 256 + (tid & 192)) * 16;
            __builtin_amdgcn_global_load_lds((const GLOBAL_AS void*)ga, (LDS_AS void*)la, 16, 0, 0);
            __builtin_amdgcn_global_load_lds((const GLOBAL_AS void*)gb, (LDS_AS void*)lb, 16, 0, 0);
        }
        __syncthreads();

#pragma unroll
        for (int kt = 0; kt < 2; ++kt) {
            bf16x8 af[4], bfr[4];
            const int kq = kt * 4 + quad;
#pragma unroll
            for (int i = 0; i < 4; ++i) {
                int ml = mwb + i * 16 + l15;
                af[i]  = *(const LDS_AS bf16x8*)(sA + (size_t)(ml * 8 + (kq ^ (ml & 7))) * 16);
                int nl = nwb + i * 16 + l15;
                bfr[i] = *(const LDS_AS bf16x8*)(sB + (size_t)(nl * 8 + (kq ^ (nl & 7))) * 16);
            }
#pragma unroll
            for (int i = 0; i < 4; ++i)
#pragma unroll
                for (int j = 0; j < 4; ++j)
                    acc[i][j] = __builtin_amdgcn_mfma_f32_16x16x32_bf16(af[i], bfr[j], acc[i][j], 0, 0, 0);
        }
        __syncthreads();
    }

    if (isxp) {
        // input-projection epilogue: add row-bias, store bf16x4 to XG[n][col][4]
#pragma unroll
        for (int im = 0; im < 4; ++im) {
#pragma unroll
            for (int jn = 0; jn < 4; ++jn) {
                const int rr  = row0 + mwb + im * 16 + quad * 4;
                const int col = bcol0 + nwb + jn * 16 + l15;
                f32x4 v = acc[im][jn];
                const int n = rr >> 2;
                f32x4 bi = *(const f32x4*)(p.bias2 + n * 4);
                bf16x4 o;
                o[0] = (bf16_t)(v[0] + bi[0]); o[1] = (bf16_t)(v[1] + bi[1]);
                o[2] = (bf16_t)(v[2] + bi[2]); o[3] = (bf16_t)(v[3] + bi[3]);
                *(bf16x4*)(p.XG2 + ((size_t)n * NXc + col) * 4) = o;
            }
        }
        return;
    }

    const bf16_t* xg = roll ? p.xg_r : p.xg_u;
    const int xo  = roll ? p.xg_off : 0;
    const int cro = roll ? p.cr_off : 0;
    const int cwo = roll ? p.cw_off : 0;
    const int nbase = row0 >> 2;                 // 32-aligned

    // fold xg into acc (coalesced bf16x4 loads, unchanged access pattern)
#pragma unroll
    for (int im = 0; im < 4; ++im)
#pragma unroll
        for (int jn = 0; jn < 4; ++jn) {
            const int rr  = row0 + mwb + im * 16 + quad * 4;
            const int col = colb * 128 + nwb + jn * 16 + l15;
            const int n = rr >> 2;
            bf16x4 xg4 = *(const bf16x4*)(xg + ((size_t)n * NXc + (col + xo)) * 4);
            acc[im][jn][0] += (float)xg4[0];
            acc[im][jn][1] += (float)xg4[1];
            acc[im][jn][2] += (float)xg4[2];
            acc[im][jn][3] += (float)xg4[3];
        }

    // LDS bounce: 64 cols x 32 n of f32x4 gates (32KB), swizzled idx,
    // two column-half passes. K-loop ended with __syncthreads -> LDS free.
    LDS_AS f32x4* sG = (LDS_AS f32x4*)smem;

#pragma unroll
    for (int pass = 0; pass < 2; ++pass) {
        if ((wave & 1) == pass) {                // this wave's cols are in this half
            const int nw = (wave >> 1) * 16;
#pragma unroll
            for (int im = 0; im < 4; ++im)
#pragma unroll
                for (int jn = 0; jn < 4; ++jn) {
                    const int n_l = nw + im * 4 + quad;
                    const int c_l = jn * 16 + l15;
                    sG[c_l * 32 + (n_l ^ (c_l & 7))] = acc[im][jn];
                }
        }
        __syncthreads();
        {
            const int c_l  = tid >> 2;           // [0,64)
            const int nb   = (tid & 3) * 8;      // [0,32) step 8
            const int colg = colb * 128 + pass * 64 + c_l;
            const fp16_t* crp = p.c_r + (size_t)(colg + cro) * Hh + nbase + nb;
            fp16x8 c8 = *(const fp16x8*)crp;     // 16B coalesced (4 lanes/col = 64B lines)
            bf16x8 h8o; fp16x8 c8o;
#pragma unroll
            for (int j = 0; j < 8; ++j) {
                f32x4 g = sG[c_l * 32 + ((nb + j) ^ (c_l & 7))];
                float c2 = sigm(g[1]) * (float)c8[j] + sigm(g[0]) * tanh_f(g[2]);
                float h2 = sigm(g[3]) * tanh_f(c2);
                c8o[j] = (fp16_t)c2;
                h8o[j] = (bf16_t)h2;
            }
            *(fp16x8*)(p.c_w + (size_t)(colg + cwo) * Hh + nbase + nb) = c8o;
            *(bf16x8*)(p.h_w + (size_t)(colg + cwo) * Hh + nbase + nb) = h8o;
        }
        if (pass == 0) __syncthreads();          // protect LDS before pass-1 writes
    }
}

// ---------------------------------------------------------------------------
// Fused setup: all independent format conversions + state zeroing in ONE
// dispatch (was 4 kernels + 2 memsets; saves 5 launch gaps + overlaps the
// BW-bound tails). Block ranges:
//   [0,16384)        cvt_w   : fp32 [4H,K] -> bf16 perm-rows (4 matrices)
//   [16384,19968)    cvt_x   : x [b*14+s][f] f32 -> x_b [s*256+b][f] bf16
//   [19968,22481)    cast Wc : f32 -> bf16 (2513*256 threads exactly)
//   [22481,22497)    cvt_bias: fused bih+bhh, perm rows
//   [22497,22753)    zero    : h0 (bf16) and c0 (fp16), 16B stores
// ---------------------------------------------------------------------------
__global__ void setup_all(const float* __restrict__ x_in,
                          const float* __restrict__ Wih_r, const float* __restrict__ Whh_r,
                          const float* __restrict__ bih_r, const float* __restrict__ bhh_r,
                          const float* __restrict__ Wih_u, const float* __restrict__ Whh_u,
                          const float* __restrict__ bih_u, const float* __restrict__ bhh_u,
                          const float* __restrict__ Wc,
                          bf16_t* __restrict__ w_ih2, bf16_t* __restrict__ w_hhr,
                          bf16_t* __restrict__ w_hhu, bf16_t* __restrict__ wc_b,
                          bf16_t* __restrict__ x_b, float* __restrict__ bias2,
                          bf16_t* __restrict__ h0, fp16_t* __restrict__ c0)
{
    const int b   = blockIdx.x;
    const int tid = threadIdx.x;

    if (b < 16384) {
        // cvt_w: idx in [0, 4*2^20)
        int idx = b * 256 + tid;
        int mat = idx >> 20;
        int r   = (idx >> 8) & 4095;
        int k4  = (idx & 255) * 4;
        int n = r >> 2, g = r & 3;
        const float* src = mat == 0 ? Wih_r : mat == 1 ? Whh_r : mat == 2 ? Wih_u : Whh_u;
        bf16_t*      dst = mat == 0 ? w_ih2 : mat == 1 ? w_hhr
                         : mat == 2 ? (w_ih2 + (size_t)4096 * Kk) : w_hhu;
        f32x4 v = *(const f32x4*)(src + (size_t)(g * Hh + n) * Kk + k4);
        bf16x4 o;
        o[0] = (bf16_t)v[0]; o[1] = (bf16_t)v[1]; o[2] = (bf16_t)v[2]; o[3] = (bf16_t)v[3];
        *(bf16x4*)(dst + (size_t)r * Kk + k4) = o;
    } else if (b < 19968) {
        // cvt_x
        int idx = (b - 16384) * 256 + tid;
        int f4  = (idx & 255) * 4;
        int row = idx >> 8;
        int s = row % 14, bb = row / 14;
        f32x4 v = *(const f32x4*)(x_in + (size_t)row * Kk + f4);
        bf16x4 o;
        o[0] = (bf16_t)v[0]; o[1] = (bf16_t)v[1]; o[2] = (bf16_t)v[2]; o[3] = (bf16_t)v[3];
        *(bf16x4*)(x_b + (size_t)(s * 256 + bb) * Kk + f4) = o;
    } else if (b < 22481) {
        // cast Wc -> bf16: exactly 2513*256 threads cover Cc*Kk/4 chunks
        int i = (b - 19968) * 256 + tid;
        f32x4 v = *(const f32x4*)(Wc + (size_t)i * 4);
        bf16x4 o;
        o[0] = (bf16_t)v[0]; o[1] = (bf16_t)v[1]; o[2] = (bf16_t)v[2]; o[3] = (bf16_t)v[3];
        *(bf16x4*)(wc_b + (size_t)i * 4) = o;
    } else if (b < 22497) {
        // cvt_bias
        int r = (b - 22481) * 256 + tid;
        int n = r >> 2, g = r & 3;
        int ir = g * Hh + n;
        bias2[r]        = bih_r[ir] + bhh_r[ir];
        bias2[4096 + r] = bih_u[ir] + bhh_u[ir];
    } else {
        // zero h0 (512KB) then c0 (512KB), 16B per thread
        int z = b - 22497;
        f32x4 zero = {0.f, 0.f, 0.f, 0.f};
        if (z < 128) {
            f32x4* d = (f32x4*)h0;
            d[(size_t)z * 256 + tid] = zero;
        } else {
            f32x4* d = (f32x4*)c0;
            d[(size_t)(z - 128) * 256 + tid] = zero;
        }
    }
}

// ---------------------------------------------------------------------------
extern "C" void kernel_launch(void* const* d_in, const int* in_sizes, int n_in,
                              void* d_out, int out_size, void* d_ws, size_t ws_size,
                              hipStream_t stream)
{
    const float* x_in  = (const float*)d_in[0];
    const float* Wih_r = (const float*)d_in[1];
    const float* Whh_r = (const float*)d_in[2];
    const float* bih_r = (const float*)d_in[3];
    const float* bhh_r = (const float*)d_in[4];
    const float* Wih_u = (const float*)d_in[5];
    const float* Whh_u = (const float*)d_in[6];
    const float* bih_u = (const float*)d_in[7];
    const float* bhh_u = (const float*)d_in[8];
    const float* Wc    = (const float*)d_in[9];
    const float* bc    = (const float*)d_in[10];
    float* out = (float*)d_out;

    char* ws = (char*)d_ws;
    size_t off = 0;
    auto alloc = [&](size_t bytes) -> char* {
        char* p = ws + off;
        off += (bytes + 255) & ~(size_t)255;
        return p;
    };

    const size_t BH = (size_t)Bb * Hh;                 // 262144 elems
    bf16_t* w_ih2  = (bf16_t*)alloc((size_t)8192 * Kk * 2);  // [roll | unroll]
    bf16_t* w_hhr  = (bf16_t*)alloc((size_t)4096 * Kk * 2);
    bf16_t* w_hhu  = (bf16_t*)alloc((size_t)4096 * Kk * 2);
    bf16_t* wc_b   = (bf16_t*)alloc((size_t)Cc * Kk * 2);
    bf16_t* x_b    = (bf16_t*)alloc((size_t)NXc * Kk * 2);
    float*  bias2  = (float*)alloc(8192 * 4);
    bf16_t* XG2    = (bf16_t*)alloc((size_t)2048 * NXc * 4 * 2);
    bf16_t* P0     = (bf16_t*)alloc((size_t)Ss * BH * 2);
    bf16_t* P1     = (bf16_t*)alloc((size_t)Ss * BH * 2);
    fp16_t* Cp0    = (fp16_t*)alloc((size_t)Ss * BH * 2);
    fp16_t* Cp1    = (fp16_t*)alloc((size_t)Ss * BH * 2);
    bf16_t* h0     = (bf16_t*)alloc(BH * 2);
    fp16_t* c0     = (fp16_t*)alloc(BH * 2);

    bf16_t* XGr = XG2;
    bf16_t* XGu = XG2 + (size_t)1024 * NXc * 4;
    bf16_t* P[2] = {P0, P1};
    fp16_t* Cp[2] = {Cp0, Cp1};

    // fused conversions + zero-init (was 4 kernels + 2 memsets)
    setup_all<<<22753, 256, 0, stream>>>(x_in, Wih_r, Whh_r, bih_r, bhh_r,
                                         Wih_u, Whh_u, bih_u, bhh_u, Wc,
                                         w_ih2, w_hhr, w_hhu, wc_b, x_b,
                                         bias2, h0, c0);

    // xproj chunk schedule: chunk c<14 = roll cols c*256; c>=14 = unroll cols
    // (c-14)*256. Deadlines: r_j in dispatch <= j, u_j in dispatch <= j+1.
    // Front-loaded to fill idle capacity of steps 1-6 to exactly 512 blocks.
    static const int xp_sched[6][7] = {
        { 1, 14,  2, 15,  3, 16,  4},   // step 1: r1 u0 r2 u1 r3 u2 r4
        {17,  5, 18,  6, 19,  7, -1},   // step 2: u3 r5 u4 r6 u5 r7
        {20,  8, 21,  9, 22, -1, -1},   // step 3: u6 r8 u7 r9 u8
        {10, 23, 11, 24, -1, -1, -1},   // step 4: r10 u9 r11 u10
        {12, 25, 13, -1, -1, -1, -1},   // step 5: r12 u11 r13
        {26, 27, -1, -1, -1, -1, -1},   // step 6: u12 u13
    };
    static const int xp_n[6] = {7, 6, 5, 4, 3, 2};

    // prologue: chunk r0 only (needed by step 1's roll epilogue)
    {
        StepArgs p{};
        p.Au = w_hhu; p.Ar = w_hhr; p.Bh = h0;
        p.xg_u = XGu; p.xg_r = XGr;
        p.c_r = c0; p.c_w = Cp[0]; p.h_w = P[0];
        p.Wih = w_ih2; p.Xb = x_b; p.bias2 = bias2; p.XG2 = XG2;
        p.UCB = 0; p.b_off = 0; p.xg_off = 0; p.cr_off = 0; p.cw_off = 0;
        p.CB = 0; p.cpg = 1;
        p.nRec = 0;
        p.xp[0] = 0;
        for (int i = 1; i < 7; ++i) p.xp[i] = -1;
        lstm_step<<<64, 256, 0, stream>>>(p);
    }

    // skewed recurrent schedule: 16 global steps, roll + lockstep unroll merged,
    // with xproj filler blocks appended to steps 1-6
    for (int k = 1; k <= 16; ++k) {
        int a = (k - 1 < 14) ? (k - 1) : 14;
        int rollk = (k <= 14) ? 1 : 0;
        StepArgs p{};
        p.Au = w_hhu;  p.Ar = w_hhr;
        p.Bh = (k == 1) ? h0 : P[(k - 1) & 1];
        p.xg_u = XGu;  p.xg_r = XGr;
        p.c_r = (k == 1) ? c0 : Cp[(k - 1) & 1];
        p.c_w = Cp[k & 1];
        p.h_w = P[k & 1];
        p.Wih = w_ih2; p.Xb = x_b; p.bias2 = bias2; p.XG2 = XG2;
        p.UCB = 2 * a;
        p.b_off  = (k >= 2) ? (k - 2) * 256 : 0;
        p.xg_off = (k - 1) * 256;
        p.cr_off = (k >= 2) ? (k - 2) * 256 : 0;
        p.cw_off = (k - 1) * 256;
        p.CB  = p.UCB + 2 * rollk;
        p.cpg = (p.CB + 3) >> 2;
        p.nRec = 8 * 16 * p.cpg;
        int nxp = (k <= 6) ? xp_n[k - 1] : 0;
        for (int i = 0; i < 7; ++i)
            p.xp[i] = (k <= 6 && i < nxp) ? xp_sched[k - 1][i] : -1;
        lstm_step<<<p.nRec + nxp * 64, 256, 0, stream>>>(p);
    }

    // classifier: A = final h states in P[0] (A-row remap), out [3584,2513]
    gemm_bt<2><<<560, 256, 0, stream>>>(P[0], wc_b, Cc, 14, 5, 4, 20,
                                        bc, nullptr, out);
}